// Round 2
// baseline (432.270 us; speedup 1.0000x reference)
//
#include <hip/hip_runtime.h>

#define DIMK 512
#define NBLK 64
#define NTOK 32768

typedef short  short8 __attribute__((ext_vector_type(8)));
typedef float  f32x4  __attribute__((ext_vector_type(4)));
typedef unsigned short u16x8 __attribute__((ext_vector_type(8)));

__device__ __forceinline__ unsigned short f2bf(float f) {
  union { float f; unsigned u; } v; v.f = f;
  unsigned r = (v.u + 0x7FFFu + ((v.u >> 16) & 1u)) >> 16;   // RNE
  return (unsigned short)r;
}
__device__ __forceinline__ float bf2f(unsigned short h) {
  return __uint_as_float(((unsigned)h) << 16);
}

// async 16B global -> LDS (wave-uniform base + lane*16; layout must be
// contiguous in lane order — ours is: LDS byte offset == chunk_id*16)
__device__ __forceinline__ void gload_lds16(const unsigned short* g,
                                            unsigned short* l) {
  __builtin_amdgcn_global_load_lds(
      (const __attribute__((address_space(1))) unsigned int*)(g),
      (__attribute__((address_space(3))) unsigned int*)(l),
      16, 0, 0);
}

// ---------------------------------------------------------------------------
// 128x128 MFMA tile body with global_load_lds staging.
// A row-major [row][k], Bt row-major [n][k] (both bf16 bits), K = 512.
// ---------------------------------------------------------------------------
__device__ __forceinline__ void gemm_tile(
    const unsigned short* __restrict__ A, size_t arow0,
    const unsigned short* __restrict__ Bt, size_t brow0,
    f32x4 acc[4][4], unsigned short* As, unsigned short* Bs)
{
  const int tid  = threadIdx.x;
  const int lane = tid & 63;
  const int wv   = tid >> 6;
  const int quad = lane >> 4;
  const int l16  = lane & 15;
  const int rb   = (wv >> 1) * 64;
  const int cb   = (wv & 1) * 64;

  const int c0 = tid, c1 = tid + 256;
  const int r0 = c0 >> 2, o0 = (c0 & 3) << 3;
  const int r1 = c1 >> 2, o1 = (c1 & 3) << 3;
  const unsigned short* a0 = &A[(arow0 + r0) * (size_t)DIMK + o0];
  const unsigned short* a1 = &A[(arow0 + r1) * (size_t)DIMK + o1];
  const unsigned short* b0 = &Bt[(brow0 + r0) * (size_t)DIMK + o0];
  const unsigned short* b1 = &Bt[(brow0 + r1) * (size_t)DIMK + o1];

  for (int it = 0; it < 16; ++it) {
    const int k0 = it * 32;
    gload_lds16(a0 + k0, &As[c0 * 8]);
    gload_lds16(a1 + k0, &As[c1 * 8]);
    gload_lds16(b0 + k0, &Bs[c0 * 8]);
    gload_lds16(b1 + k0, &Bs[c1 * 8]);
    __syncthreads();
    short8 af[4], bfv[4];
#pragma unroll
    for (int i = 0; i < 4; ++i)
      af[i] = *(const short8*)&As[(rb + i * 16 + l16) * 32 + quad * 8];
#pragma unroll
    for (int j = 0; j < 4; ++j)
      bfv[j] = *(const short8*)&Bs[(cb + j * 16 + l16) * 32 + quad * 8];
#pragma unroll
    for (int i = 0; i < 4; ++i)
#pragma unroll
      for (int j = 0; j < 4; ++j)
        acc[i][j] = __builtin_amdgcn_mfma_f32_16x16x32_bf16(
            af[i], bfv[j], acc[i][j], 0, 0, 0);
    __syncthreads();
  }
}

// ---------------------------------------------------------------------------
// K0a: Wt[w][n][k] = bf16(dw_w[k][n])
// ---------------------------------------------------------------------------
__global__ __launch_bounds__(256) void k_wt_prep(
    const float* __restrict__ dw1, const float* __restrict__ dw2,
    const float* __restrict__ dw3, unsigned short* __restrict__ Wt)
{
  const int idx = blockIdx.x * 256 + threadIdx.x;
  const int w = idx >> 18;
  const int r = idx & 262143;
  const int n = r >> 9, k = r & 511;
  const float* dw = (w == 0) ? dw1 : (w == 1) ? dw2 : dw3;
  Wt[(size_t)w * 262144 + (size_t)n * 512 + k] = f2bf(dw[(size_t)k * 512 + n]);
}

// ---------------------------------------------------------------------------
// K0b: X fp32 -> bf16 bits
// ---------------------------------------------------------------------------
__global__ __launch_bounds__(256) void k_xconv(
    const float* __restrict__ X, unsigned short* __restrict__ Xb)
{
  const size_t i = ((size_t)blockIdx.x * 256 + threadIdx.x) * 8;
  const float4 a = *(const float4*)(X + i);
  const float4 b = *(const float4*)(X + i + 4);
  u16x8 o;
  o[0] = f2bf(a.x); o[1] = f2bf(a.y); o[2] = f2bf(a.z); o[3] = f2bf(a.w);
  o[4] = f2bf(b.x); o[5] = f2bf(b.y); o[6] = f2bf(b.z); o[7] = f2bf(b.w);
  *(u16x8*)(Xb + i) = o;
}

// ---------------------------------------------------------------------------
// K1: Q/K/V = Xb @ dw_w + db_w
// ---------------------------------------------------------------------------
__global__ __launch_bounds__(256) void k_qkv(
    const unsigned short* __restrict__ Xb, const unsigned short* __restrict__ Wt,
    const float* __restrict__ db1, const float* __restrict__ db2,
    const float* __restrict__ db3,
    unsigned short* __restrict__ Qb, unsigned short* __restrict__ Kb,
    unsigned short* __restrict__ Vb)
{
  __shared__ __align__(16) unsigned short As[128 * 32];
  __shared__ __align__(16) unsigned short Bs[128 * 32];
  const int w  = blockIdx.x >> 2;
  const int nt = blockIdx.x & 3;
  const size_t m0 = (size_t)blockIdx.y * 128;
  const int n0 = nt * 128;
  f32x4 acc[4][4];
#pragma unroll
  for (int i = 0; i < 4; ++i)
#pragma unroll
    for (int j = 0; j < 4; ++j) { f32x4 z = {0.f, 0.f, 0.f, 0.f}; acc[i][j] = z; }

  gemm_tile(Xb, m0, Wt + (size_t)w * 262144, (size_t)n0, acc, As, Bs);

  const float* db = (w == 0) ? db1 : (w == 1) ? db2 : db3;
  unsigned short* Ob = (w == 0) ? Qb : (w == 1) ? Kb : Vb;
  const int lane = threadIdx.x & 63, wv = threadIdx.x >> 6;
  const int quad = lane >> 4, l16 = lane & 15;
  const int rb = (wv >> 1) * 64, cb = (wv & 1) * 64;
#pragma unroll
  for (int i = 0; i < 4; ++i)
#pragma unroll
    for (int j = 0; j < 4; ++j)
#pragma unroll
      for (int r = 0; r < 4; ++r) {
        const size_t row = m0 + rb + i * 16 + quad * 4 + r;
        const int col = n0 + cb + j * 16 + l16;
        Ob[row * (size_t)DIMK + col] = f2bf(acc[i][j][r] + db[col]);
      }
}

// ---------------------------------------------------------------------------
// T: in-place per-block transpose of V (512x512 bf16 per block)
// ---------------------------------------------------------------------------
__global__ __launch_bounds__(256) void k_vt(unsigned short* __restrict__ Vb)
{
  const int ti = blockIdx.x >> 4, tj = blockIdx.x & 15;
  if (ti > tj) return;
  unsigned short* V = Vb + (size_t)blockIdx.y * 262144;
  __shared__ unsigned short TA[32][33];
  __shared__ unsigned short TB[32][33];
  const int c = threadIdx.x & 31, r0 = (threadIdx.x >> 5) * 4;
#pragma unroll
  for (int i = 0; i < 4; ++i)
    TA[r0 + i][c] = V[(size_t)(ti * 32 + r0 + i) * 512 + tj * 32 + c];
  if (ti != tj) {
#pragma unroll
    for (int i = 0; i < 4; ++i)
      TB[r0 + i][c] = V[(size_t)(tj * 32 + r0 + i) * 512 + ti * 32 + c];
  }
  __syncthreads();
  if (ti != tj) {
#pragma unroll
    for (int i = 0; i < 4; ++i)
      V[(size_t)(ti * 32 + r0 + i) * 512 + tj * 32 + c] = TB[c][r0 + i];
#pragma unroll
    for (int i = 0; i < 4; ++i)
      V[(size_t)(tj * 32 + r0 + i) * 512 + ti * 32 + c] = TA[c][r0 + i];
  } else {
#pragma unroll
    for (int i = 0; i < 4; ++i)
      V[(size_t)(ti * 32 + r0 + i) * 512 + tj * 32 + c] = TA[c][r0 + i];
  }
}

// ---------------------------------------------------------------------------
// K2: fused scores + mask + softmax -> P (bf16).
// Block = 64 queries x ALL 512 keys of one attention block.
// grid: (8 mtiles, 64 blks). Wave wv covers cols [wv*128, wv*128+128).
// ---------------------------------------------------------------------------
__global__ __launch_bounds__(256, 2) void k_attn_p(
    const unsigned short* __restrict__ Qb, const unsigned short* __restrict__ Kb,
    const float* __restrict__ mask, unsigned short* __restrict__ Pb)
{
  __shared__ __align__(16) unsigned short As[64 * 32];     // 4 KB
  __shared__ __align__(16) unsigned short Bs[512 * 32];    // 32 KB
  __shared__ float red[4][64];
  const int tid = threadIdx.x, lane = tid & 63, wv = tid >> 6;
  const int quad = lane >> 4, l16 = lane & 15;
  const int mt = blockIdx.x, blk = blockIdx.y;
  const size_t tb = (size_t)blk * 512;
  const size_t q0 = tb + (size_t)mt * 64;

  f32x4 acc[4][8];
#pragma unroll
  for (int i = 0; i < 4; ++i)
#pragma unroll
    for (int j = 0; j < 8; ++j) { f32x4 z = {0.f, 0.f, 0.f, 0.f}; acc[i][j] = z; }

  const int ca = tid;                          // 256 A-chunks (64 rows x 4)
  const int ra = ca >> 2, oa = (ca & 3) << 3;
  const unsigned short* ap = &Qb[(q0 + ra) * (size_t)DIMK + oa];
  const unsigned short* kp = &Kb[tb * (size_t)DIMK];

  for (int it = 0; it < 16; ++it) {
    const int k0 = it * 32;
    gload_lds16(ap + k0, &As[ca * 8]);
#pragma unroll
    for (int h = 0; h < 8; ++h) {
      const int c = tid + h * 256;
      const int r = c >> 2, o = (c & 3) << 3;
      gload_lds16(kp + (size_t)r * DIMK + k0 + o, &Bs[c * 8]);
    }
    __syncthreads();
    short8 af[4], bfv[8];
#pragma unroll
    for (int i = 0; i < 4; ++i)
      af[i] = *(const short8*)&As[(i * 16 + l16) * 32 + quad * 8];
#pragma unroll
    for (int j = 0; j < 8; ++j)
      bfv[j] = *(const short8*)&Bs[(wv * 128 + j * 16 + l16) * 32 + quad * 8];
#pragma unroll
    for (int i = 0; i < 4; ++i)
#pragma unroll
      for (int j = 0; j < 8; ++j)
        acc[i][j] = __builtin_amdgcn_mfma_f32_16x16x32_bf16(
            af[i], bfv[j], acc[i][j], 0, 0, 0);
    __syncthreads();
  }

  // ---- epilogue: scale + mask + row softmax over 512 keys ----
  const float scale = 0.04419417382415922f;    // 1/sqrt(512)
  float rmax[4][4];
#pragma unroll
  for (int i = 0; i < 4; ++i)
#pragma unroll
    for (int r = 0; r < 4; ++r) rmax[i][r] = -3.0e38f;
#pragma unroll
  for (int i = 0; i < 4; ++i)
#pragma unroll
    for (int j = 0; j < 8; ++j)
#pragma unroll
      for (int r = 0; r < 4; ++r) {
        const size_t tok = q0 + i * 16 + quad * 4 + r;
        const int col = wv * 128 + j * 16 + l16;
        const float m = mask[tok * (size_t)DIMK + col];
        const float v = acc[i][j][r] * scale + (1.0f - m) * (-1e10f);
        acc[i][j][r] = v;
        rmax[i][r] = fmaxf(rmax[i][r], v);
      }
  // reduce max over l16 (xor bits 1,2,4,8 keep quad fixed)
#pragma unroll
  for (int i = 0; i < 4; ++i)
#pragma unroll
    for (int r = 0; r < 4; ++r)
      for (int d = 1; d < 16; d <<= 1)
        rmax[i][r] = fmaxf(rmax[i][r], __shfl_xor(rmax[i][r], d, 64));
  if (l16 == 0)
#pragma unroll
    for (int i = 0; i < 4; ++i)
#pragma unroll
      for (int r = 0; r < 4; ++r) red[wv][i * 16 + quad * 4 + r] = rmax[i][r];
  __syncthreads();
#pragma unroll
  for (int i = 0; i < 4; ++i)
#pragma unroll
    for (int r = 0; r < 4; ++r) {
      const int row = i * 16 + quad * 4 + r;
      rmax[i][r] = fmaxf(fmaxf(red[0][row], red[1][row]),
                         fmaxf(red[2][row], red[3][row]));
    }
  __syncthreads();   // red reused for sums
  float rsum[4][4];
#pragma unroll
  for (int i = 0; i < 4; ++i)
#pragma unroll
    for (int r = 0; r < 4; ++r) rsum[i][r] = 0.f;
#pragma unroll
  for (int i = 0; i < 4; ++i)
#pragma unroll
    for (int j = 0; j < 8; ++j)
#pragma unroll
      for (int r = 0; r < 4; ++r) {
        const float e = __expf(acc[i][j][r] - rmax[i][r]);
        acc[i][j][r] = e;
        rsum[i][r] += e;
      }
#pragma unroll
  for (int i = 0; i < 4; ++i)
#pragma unroll
    for (int r = 0; r < 4; ++r)
      for (int d = 1; d < 16; d <<= 1)
        rsum[i][r] += __shfl_xor(rsum[i][r], d, 64);
  if (l16 == 0)
#pragma unroll
    for (int i = 0; i < 4; ++i)
#pragma unroll
      for (int r = 0; r < 4; ++r) red[wv][i * 16 + quad * 4 + r] = rsum[i][r];
  __syncthreads();
#pragma unroll
  for (int i = 0; i < 4; ++i)
#pragma unroll
    for (int r = 0; r < 4; ++r) {
      const int row = i * 16 + quad * 4 + r;
      rsum[i][r] = 1.0f / (red[0][row] + red[1][row] + red[2][row] + red[3][row]);
    }
#pragma unroll
  for (int i = 0; i < 4; ++i)
#pragma unroll
    for (int j = 0; j < 8; ++j)
#pragma unroll
      for (int r = 0; r < 4; ++r) {
        const size_t tok = q0 + i * 16 + quad * 4 + r;
        const int col = wv * 128 + j * 16 + l16;
        Pb[tok * (size_t)DIMK + col] = f2bf(acc[i][j][r] * rsum[i][r]);
      }
}

// ---------------------------------------------------------------------------
// K3: fused PV + residual + LayerNorm -> Out (fp32).
// Block = 64 tokens x all 512 dims; Vt per-block [dim][tok].
// grid: (8 mtiles, 64 blks).
// ---------------------------------------------------------------------------
__global__ __launch_bounds__(256, 2) void k_pv_ln(
    const unsigned short* __restrict__ Pb, const unsigned short* __restrict__ Vt,
    const float* __restrict__ X, float* __restrict__ Out)
{
  __shared__ __align__(16) unsigned short As[64 * 32];
  __shared__ __align__(16) unsigned short Bs[512 * 32];
  __shared__ float2 red[4][64];
  const int tid = threadIdx.x, lane = tid & 63, wv = tid >> 6;
  const int quad = lane >> 4, l16 = lane & 15;
  const int mt = blockIdx.x, blk = blockIdx.y;
  const size_t tb = (size_t)blk * 512;
  const size_t q0 = tb + (size_t)mt * 64;

  f32x4 acc[4][8];
#pragma unroll
  for (int i = 0; i < 4; ++i)
#pragma unroll
    for (int j = 0; j < 8; ++j) { f32x4 z = {0.f, 0.f, 0.f, 0.f}; acc[i][j] = z; }

  const int ca = tid;
  const int ra = ca >> 2, oa = (ca & 3) << 3;
  const unsigned short* ap = &Pb[(q0 + ra) * (size_t)DIMK + oa];
  const unsigned short* vp = Vt + (size_t)blk * 262144;   // [d][tok]

  for (int it = 0; it < 16; ++it) {
    const int k0 = it * 32;
    gload_lds16(ap + k0, &As[ca * 8]);
#pragma unroll
    for (int h = 0; h < 8; ++h) {
      const int c = tid + h * 256;
      const int r = c >> 2, o = (c & 3) << 3;
      gload_lds16(vp + (size_t)r * DIMK + k0 + o, &Bs[c * 8]);
    }
    __syncthreads();
    short8 af[4], bfv[8];
#pragma unroll
    for (int i = 0; i < 4; ++i)
      af[i] = *(const short8*)&As[(i * 16 + l16) * 32 + quad * 8];
#pragma unroll
    for (int j = 0; j < 8; ++j)
      bfv[j] = *(const short8*)&Bs[(wv * 128 + j * 16 + l16) * 32 + quad * 8];
#pragma unroll
    for (int i = 0; i < 4; ++i)
#pragma unroll
      for (int j = 0; j < 8; ++j)
        acc[i][j] = __builtin_amdgcn_mfma_f32_16x16x32_bf16(
            af[i], bfv[j], acc[i][j], 0, 0, 0);
    __syncthreads();
  }

  // ---- epilogue: + residual, LayerNorm over 512 dims ----
  float vsum[4][4], vsq[4][4];
#pragma unroll
  for (int i = 0; i < 4; ++i)
#pragma unroll
    for (int r = 0; r < 4; ++r) { vsum[i][r] = 0.f; vsq[i][r] = 0.f; }
#pragma unroll
  for (int i = 0; i < 4; ++i)
#pragma unroll
    for (int j = 0; j < 8; ++j)
#pragma unroll
      for (int r = 0; r < 4; ++r) {
        const size_t tok = q0 + i * 16 + quad * 4 + r;
        const int col = wv * 128 + j * 16 + l16;
        const float v = acc[i][j][r] + X[tok * (size_t)DIMK + col];
        acc[i][j][r] = v;
        vsum[i][r] += v;
        vsq[i][r] += v * v;
      }
#pragma unroll
  for (int i = 0; i < 4; ++i)
#pragma unroll
    for (int r = 0; r < 4; ++r)
      for (int d = 1; d < 16; d <<= 1) {
        vsum[i][r] += __shfl_xor(vsum[i][r], d, 64);
        vsq[i][r]  += __shfl_xor(vsq[i][r], d, 64);
      }
  if (l16 == 0)
#pragma unroll
    for (int i = 0; i < 4; ++i)
#pragma unroll
      for (int r = 0; r < 4; ++r) {
        float2 p; p.x = vsum[i][r]; p.y = vsq[i][r];
        red[wv][i * 16 + quad * 4 + r] = p;
      }
  __syncthreads();
#pragma unroll
  for (int i = 0; i < 4; ++i)
#pragma unroll
    for (int r = 0; r < 4; ++r) {
      const int row = i * 16 + quad * 4 + r;
      float s = 0.f, q = 0.f;
#pragma unroll
      for (int w = 0; w < 4; ++w) { s += red[w][row].x; q += red[w][row].y; }
      const float mean = s * (1.0f / 512.0f);
      const float var  = q * (1.0f / 512.0f) - mean * mean;
      vsum[i][r] = mean;
      vsq[i][r]  = rsqrtf(var + 1e-3f);
    }
#pragma unroll
  for (int i = 0; i < 4; ++i)
#pragma unroll
    for (int j = 0; j < 8; ++j)
#pragma unroll
      for (int r = 0; r < 4; ++r) {
        const size_t tok = q0 + i * 16 + quad * 4 + r;
        const int col = wv * 128 + j * 16 + l16;
        Out[tok * (size_t)DIMK + col] =
            (acc[i][j][r] - vsum[i][r]) * vsq[i][r];
      }
}

// ---------------------------------------------------------------------------
extern "C" void kernel_launch(void* const* d_in, const int* in_sizes, int n_in,
                              void* d_out, int out_size, void* d_ws, size_t ws_size,
                              hipStream_t stream)
{
  const float* X    = (const float*)d_in[0];
  const float* mask = (const float*)d_in[1];
  const float* dw1  = (const float*)d_in[2];
  const float* dw2  = (const float*)d_in[3];
  const float* dw3  = (const float*)d_in[4];
  const float* db1  = (const float*)d_in[5];
  const float* db2  = (const float*)d_in[6];
  const float* db3  = (const float*)d_in[7];
  float* Out = (float*)d_out;

  char* ws = (char*)d_ws;
  const size_t MB = 1ull << 20;
  // ws layout:
  //   [0,2MB)    Wt : 3x512x512 bf16 transposed weights
  //   [2,34)     Qb
  //   [34,66)    Kb
  //   [66,98)    Vb (transposed in place per block by k_vt)
  //   [98,130)   Pb ; earlier aliased as Xb (bf16 input, dead after k_qkv)
  unsigned short* Wt = (unsigned short*)(ws);
  unsigned short* Qb = (unsigned short*)(ws + 2 * MB);
  unsigned short* Kb = (unsigned short*)(ws + 34 * MB);
  unsigned short* Vb = (unsigned short*)(ws + 66 * MB);
  unsigned short* Pb = (unsigned short*)(ws + 98 * MB);
  unsigned short* Xb = Pb;   // alias: dead once k_qkv completes

  k_wt_prep<<<3072, 256, 0, stream>>>(dw1, dw2, dw3, Wt);
  k_xconv  <<<8192, 256, 0, stream>>>(X, Xb);
  k_qkv    <<<dim3(12, 256), 256, 0, stream>>>(Xb, Wt, db1, db2, db3, Qb, Kb, Vb);
  k_vt     <<<dim3(256, 64), 256, 0, stream>>>(Vb);
  k_attn_p <<<dim3(8, 64), 256, 0, stream>>>(Qb, Kb, mask, Pb);
  k_pv_ln  <<<dim3(8, 64), 256, 0, stream>>>(Pb, Vb, X, Out);
  k_ln_unused:;
}

// Round 3
// 352.343 us; speedup vs baseline: 1.2268x; 1.2268x over previous
//
#include <hip/hip_runtime.h>

#define DIMK 512
#define NBLK 64
#define NTOK 32768

typedef short  short8 __attribute__((ext_vector_type(8)));
typedef float  f32x4  __attribute__((ext_vector_type(4)));
typedef unsigned short u16x8 __attribute__((ext_vector_type(8)));

__device__ __forceinline__ unsigned short f2bf(float f) {
  union { float f; unsigned u; } v; v.f = f;
  unsigned r = (v.u + 0x7FFFu + ((v.u >> 16) & 1u)) >> 16;   // RNE
  return (unsigned short)r;
}

// async 16B global -> LDS (wave-uniform base + lane*16)
__device__ __forceinline__ void gload_lds16(const unsigned short* g,
                                            unsigned short* l) {
  __builtin_amdgcn_global_load_lds(
      (const __attribute__((address_space(1))) unsigned int*)(g),
      (__attribute__((address_space(3))) unsigned int*)(l),
      16, 0, 0);
}

// ---------------------------------------------------------------------------
// 128x128 MFMA tile body, global_load_lds staging. A[row][k], Bt[n][k], K=512.
// ---------------------------------------------------------------------------
__device__ __forceinline__ void gemm_tile(
    const unsigned short* __restrict__ A, size_t arow0,
    const unsigned short* __restrict__ Bt, size_t brow0,
    f32x4 acc[4][4], unsigned short* As, unsigned short* Bs)
{
  const int tid  = threadIdx.x;
  const int lane = tid & 63;
  const int wv   = tid >> 6;
  const int quad = lane >> 4;
  const int l16  = lane & 15;
  const int rb   = (wv >> 1) * 64;
  const int cb   = (wv & 1) * 64;

  const int c0 = tid, c1 = tid + 256;
  const int r0 = c0 >> 2, o0 = (c0 & 3) << 3;
  const int r1 = c1 >> 2, o1 = (c1 & 3) << 3;
  const unsigned short* a0 = &A[(arow0 + r0) * (size_t)DIMK + o0];
  const unsigned short* a1 = &A[(arow0 + r1) * (size_t)DIMK + o1];
  const unsigned short* b0 = &Bt[(brow0 + r0) * (size_t)DIMK + o0];
  const unsigned short* b1 = &Bt[(brow0 + r1) * (size_t)DIMK + o1];

  for (int it = 0; it < 16; ++it) {
    const int k0 = it * 32;
    gload_lds16(a0 + k0, &As[c0 * 8]);
    gload_lds16(a1 + k0, &As[c1 * 8]);
    gload_lds16(b0 + k0, &Bs[c0 * 8]);
    gload_lds16(b1 + k0, &Bs[c1 * 8]);
    __syncthreads();
    short8 af[4], bfv[4];
#pragma unroll
    for (int i = 0; i < 4; ++i)
      af[i] = *(const short8*)&As[(rb + i * 16 + l16) * 32 + quad * 8];
#pragma unroll
    for (int j = 0; j < 4; ++j)
      bfv[j] = *(const short8*)&Bs[(cb + j * 16 + l16) * 32 + quad * 8];
#pragma unroll
    for (int i = 0; i < 4; ++i)
#pragma unroll
      for (int j = 0; j < 4; ++j)
        acc[i][j] = __builtin_amdgcn_mfma_f32_16x16x32_bf16(
            af[i], bfv[j], acc[i][j], 0, 0, 0);
    __syncthreads();
  }
}

// ---------------------------------------------------------------------------
// K0a: Wt[w][n][k] = bf16(dw_w[k][n])
// ---------------------------------------------------------------------------
__global__ __launch_bounds__(256) void k_wt_prep(
    const float* __restrict__ dw1, const float* __restrict__ dw2,
    const float* __restrict__ dw3, unsigned short* __restrict__ Wt)
{
  const int idx = blockIdx.x * 256 + threadIdx.x;
  const int w = idx >> 18;
  const int r = idx & 262143;
  const int n = r >> 9, k = r & 511;
  const float* dw = (w == 0) ? dw1 : (w == 1) ? dw2 : dw3;
  Wt[(size_t)w * 262144 + (size_t)n * 512 + k] = f2bf(dw[(size_t)k * 512 + n]);
}

// ---------------------------------------------------------------------------
// K0b: X fp32 -> bf16; optionally pack mask {0,1} -> bitmask (1 byte / thread)
// ---------------------------------------------------------------------------
template<bool PACK>
__global__ __launch_bounds__(256) void k_xconv(
    const float* __restrict__ X, const float* __restrict__ mask,
    unsigned short* __restrict__ Xb, unsigned char* __restrict__ bits)
{
  const size_t gid = (size_t)blockIdx.x * 256 + threadIdx.x;
  const size_t i = gid * 8;
  const float4 a = *(const float4*)(X + i);
  const float4 b = *(const float4*)(X + i + 4);
  u16x8 o;
  o[0] = f2bf(a.x); o[1] = f2bf(a.y); o[2] = f2bf(a.z); o[3] = f2bf(a.w);
  o[4] = f2bf(b.x); o[5] = f2bf(b.y); o[6] = f2bf(b.z); o[7] = f2bf(b.w);
  *(u16x8*)(Xb + i) = o;
  if (PACK) {
    const float4 ma = *(const float4*)(mask + i);
    const float4 mb = *(const float4*)(mask + i + 4);
    unsigned v = 0;
    v |= (ma.x > 0.5f) << 0; v |= (ma.y > 0.5f) << 1;
    v |= (ma.z > 0.5f) << 2; v |= (ma.w > 0.5f) << 3;
    v |= (mb.x > 0.5f) << 4; v |= (mb.y > 0.5f) << 5;
    v |= (mb.z > 0.5f) << 6; v |= (mb.w > 0.5f) << 7;
    bits[gid] = (unsigned char)v;
  }
}

// ---------------------------------------------------------------------------
// K1: Q/K/V = Xb @ dw_w + db_w.  Flat grid 3072, XCD-coherent decode:
// mtile = id & 255 (A-tile sharers land on same XCD), wnt = id >> 8.
// V written TRANSPOSED per block: Vt[blk][dim][tok].
// ---------------------------------------------------------------------------
__global__ __launch_bounds__(256) void k_qkv(
    const unsigned short* __restrict__ Xb, const unsigned short* __restrict__ Wt,
    const float* __restrict__ db1, const float* __restrict__ db2,
    const float* __restrict__ db3,
    unsigned short* __restrict__ Qb, unsigned short* __restrict__ Kb,
    unsigned short* __restrict__ Vt)
{
  __shared__ __align__(16) unsigned short As[128 * 32];
  __shared__ __align__(16) unsigned short Bs[128 * 32];
  const int id = blockIdx.x;
  const int mtile = id & 255;
  const int wnt = id >> 8;           // 0..11
  const int w  = wnt >> 2;
  const int nt = wnt & 3;
  const size_t m0 = (size_t)mtile * 128;
  const int n0 = nt * 128;
  f32x4 acc[4][4];
#pragma unroll
  for (int i = 0; i < 4; ++i)
#pragma unroll
    for (int j = 0; j < 4; ++j) { f32x4 z = {0.f, 0.f, 0.f, 0.f}; acc[i][j] = z; }

  gemm_tile(Xb, m0, Wt + (size_t)w * 262144, (size_t)n0, acc, As, Bs);

  const float* db = (w == 0) ? db1 : (w == 1) ? db2 : db3;
  const int lane = threadIdx.x & 63, wvq = threadIdx.x >> 6;
  const int quad = lane >> 4, l16 = lane & 15;
  const int rb = (wvq >> 1) * 64, cb = (wvq & 1) * 64;

  if (w < 2) {
    unsigned short* Ob = (w == 0) ? Qb : Kb;
#pragma unroll
    for (int i = 0; i < 4; ++i)
#pragma unroll
      for (int j = 0; j < 4; ++j)
#pragma unroll
        for (int r = 0; r < 4; ++r) {
          const size_t row = m0 + rb + i * 16 + quad * 4 + r;
          const int col = n0 + cb + j * 16 + l16;
          Ob[row * (size_t)DIMK + col] = f2bf(acc[i][j][r] + db[col]);
        }
  } else {
    // V transposed: Vt[blk][col][tokloc], 4 consecutive tokens per store
    const int blk = (int)(m0 >> 9);
    unsigned short* Vblk = Vt + (size_t)blk * 262144;
#pragma unroll
    for (int i = 0; i < 4; ++i)
#pragma unroll
      for (int j = 0; j < 4; ++j) {
        const int col = n0 + cb + j * 16 + l16;
        const int tokloc = (int)((m0 & 511)) + rb + i * 16 + quad * 4;
        const float bv = db[col];
        ushort4 pk;
        pk.x = f2bf(acc[i][j][0] + bv);
        pk.y = f2bf(acc[i][j][1] + bv);
        pk.z = f2bf(acc[i][j][2] + bv);
        pk.w = f2bf(acc[i][j][3] + bv);
        *(ushort4*)&Vblk[(size_t)col * 512 + tokloc] = pk;
      }
  }
}

// ---------------------------------------------------------------------------
// K2: fused scores + mask + softmax -> P (bf16).
// Flat grid 512, XCD-coherent: blk = id & 63, mt = id >> 6.
// Block = 64 queries x 512 keys; wave wv covers cols [wv*128, wv*128+128).
// ---------------------------------------------------------------------------
template<bool USE_BITS>
__global__ __launch_bounds__(256, 2) void k_attn_p(
    const unsigned short* __restrict__ Qb, const unsigned short* __restrict__ Kb,
    const float* __restrict__ mask, const unsigned long long* __restrict__ bits,
    unsigned short* __restrict__ Pb)
{
  __shared__ __align__(16) unsigned short As[64 * 32];     // 4 KB
  __shared__ __align__(16) unsigned short Bs[512 * 32];    // 32 KB
  __shared__ float red[4][64];
  const int tid = threadIdx.x, lane = tid & 63, wv = tid >> 6;
  const int quad = lane >> 4, l16 = lane & 15;
  const int blk = blockIdx.x & 63, mt = blockIdx.x >> 6;
  const size_t tb = (size_t)blk * 512;
  const size_t q0 = tb + (size_t)mt * 64;

  f32x4 acc[4][8];
#pragma unroll
  for (int i = 0; i < 4; ++i)
#pragma unroll
    for (int j = 0; j < 8; ++j) { f32x4 z = {0.f, 0.f, 0.f, 0.f}; acc[i][j] = z; }

  const int ra = tid >> 2, oa = (tid & 3) << 3;
  const unsigned short* ap = &Qb[(q0 + ra) * (size_t)DIMK + oa];
  const unsigned short* kp = &Kb[tb * (size_t)DIMK];

  for (int it = 0; it < 16; ++it) {
    const int k0 = it * 32;
    gload_lds16(ap + k0, &As[tid * 8]);
#pragma unroll
    for (int h = 0; h < 8; ++h) {
      const int c = tid + h * 256;
      const int r = c >> 2, o = (c & 3) << 3;
      gload_lds16(kp + (size_t)r * DIMK + k0 + o, &Bs[c * 8]);
    }
    __syncthreads();
    short8 af[4], bfv[8];
#pragma unroll
    for (int i = 0; i < 4; ++i)
      af[i] = *(const short8*)&As[(i * 16 + l16) * 32 + quad * 8];
#pragma unroll
    for (int j = 0; j < 8; ++j)
      bfv[j] = *(const short8*)&Bs[(wv * 128 + j * 16 + l16) * 32 + quad * 8];
#pragma unroll
    for (int i = 0; i < 4; ++i)
#pragma unroll
      for (int j = 0; j < 8; ++j)
        acc[i][j] = __builtin_amdgcn_mfma_f32_16x16x32_bf16(
            af[i], bfv[j], acc[i][j], 0, 0, 0);
    __syncthreads();
  }

  // ---- epilogue: scale + mask + row softmax over 512 keys ----
  const float scale = 0.04419417382415922f;    // 1/sqrt(512)
  float rmax[4][4];
#pragma unroll
  for (int i = 0; i < 4; ++i)
#pragma unroll
    for (int r = 0; r < 4; ++r) rmax[i][r] = -3.0e38f;
#pragma unroll
  for (int i = 0; i < 4; ++i)
#pragma unroll
    for (int r = 0; r < 4; ++r) {
      const size_t tok = q0 + i * 16 + quad * 4 + r;
      unsigned long long w0 = 0, w1 = 0;
      if (USE_BITS) {
        w0 = bits[tok * 8 + wv * 2];
        w1 = bits[tok * 8 + wv * 2 + 1];
      }
#pragma unroll
      for (int j = 0; j < 8; ++j) {
        float bias;
        if (USE_BITS) {
          const unsigned long long sel = (j < 4) ? w0 : w1;
          bias = ((sel >> (l16 + 16 * (j & 3))) & 1ull) ? 0.0f : -1e10f;
        } else {
          const int col = wv * 128 + j * 16 + l16;
          bias = (1.0f - mask[tok * (size_t)DIMK + col]) * (-1e10f);
        }
        const float v = acc[i][j][r] * scale + bias;
        acc[i][j][r] = v;
        rmax[i][r] = fmaxf(rmax[i][r], v);
      }
    }
#pragma unroll
  for (int i = 0; i < 4; ++i)
#pragma unroll
    for (int r = 0; r < 4; ++r)
      for (int d = 1; d < 16; d <<= 1)
        rmax[i][r] = fmaxf(rmax[i][r], __shfl_xor(rmax[i][r], d, 64));
  if (l16 == 0)
#pragma unroll
    for (int i = 0; i < 4; ++i)
#pragma unroll
      for (int r = 0; r < 4; ++r) red[wv][i * 16 + quad * 4 + r] = rmax[i][r];
  __syncthreads();
#pragma unroll
  for (int i = 0; i < 4; ++i)
#pragma unroll
    for (int r = 0; r < 4; ++r) {
      const int row = i * 16 + quad * 4 + r;
      rmax[i][r] = fmaxf(fmaxf(red[0][row], red[1][row]),
                         fmaxf(red[2][row], red[3][row]));
    }
  __syncthreads();
  float rsum[4][4];
#pragma unroll
  for (int i = 0; i < 4; ++i)
#pragma unroll
    for (int r = 0; r < 4; ++r) rsum[i][r] = 0.f;
#pragma unroll
  for (int i = 0; i < 4; ++i)
#pragma unroll
    for (int j = 0; j < 8; ++j)
#pragma unroll
      for (int r = 0; r < 4; ++r) {
        const float e = __expf(acc[i][j][r] - rmax[i][r]);
        acc[i][j][r] = e;
        rsum[i][r] += e;
      }
#pragma unroll
  for (int i = 0; i < 4; ++i)
#pragma unroll
    for (int r = 0; r < 4; ++r)
      for (int d = 1; d < 16; d <<= 1)
        rsum[i][r] += __shfl_xor(rsum[i][r], d, 64);
  if (l16 == 0)
#pragma unroll
    for (int i = 0; i < 4; ++i)
#pragma unroll
      for (int r = 0; r < 4; ++r) red[wv][i * 16 + quad * 4 + r] = rsum[i][r];
  __syncthreads();
#pragma unroll
  for (int i = 0; i < 4; ++i)
#pragma unroll
    for (int r = 0; r < 4; ++r) {
      const int row = i * 16 + quad * 4 + r;
      rsum[i][r] = 1.0f / (red[0][row] + red[1][row] + red[2][row] + red[3][row]);
    }
#pragma unroll
  for (int i = 0; i < 4; ++i)
#pragma unroll
    for (int j = 0; j < 8; ++j)
#pragma unroll
      for (int r = 0; r < 4; ++r) {
        const size_t tok = q0 + i * 16 + quad * 4 + r;
        const int col = wv * 128 + j * 16 + l16;
        Pb[tok * (size_t)DIMK + col] = f2bf(acc[i][j][r] * rsum[i][r]);
      }
}

// ---------------------------------------------------------------------------
// K3: fused PV + residual + LayerNorm -> Out (fp32).
// Flat grid 512, XCD-coherent: blk = id & 63, mt = id >> 6.
// ---------------------------------------------------------------------------
__global__ __launch_bounds__(256, 2) void k_pv_ln(
    const unsigned short* __restrict__ Pb, const unsigned short* __restrict__ Vt,
    const float* __restrict__ X, float* __restrict__ Out)
{
  __shared__ __align__(16) unsigned short As[64 * 32];
  __shared__ __align__(16) unsigned short Bs[512 * 32];
  __shared__ float2 red[4][64];
  const int tid = threadIdx.x, lane = tid & 63, wv = tid >> 6;
  const int quad = lane >> 4, l16 = lane & 15;
  const int blk = blockIdx.x & 63, mt = blockIdx.x >> 6;
  const size_t tb = (size_t)blk * 512;
  const size_t q0 = tb + (size_t)mt * 64;

  f32x4 acc[4][8];
#pragma unroll
  for (int i = 0; i < 4; ++i)
#pragma unroll
    for (int j = 0; j < 8; ++j) { f32x4 z = {0.f, 0.f, 0.f, 0.f}; acc[i][j] = z; }

  const int ra = tid >> 2, oa = (tid & 3) << 3;
  const unsigned short* ap = &Pb[(q0 + ra) * (size_t)DIMK + oa];
  const unsigned short* vp = Vt + (size_t)blk * 262144;   // [d][tok]

  for (int it = 0; it < 16; ++it) {
    const int k0 = it * 32;
    gload_lds16(ap + k0, &As[tid * 8]);
#pragma unroll
    for (int h = 0; h < 8; ++h) {
      const int c = tid + h * 256;
      const int r = c >> 2, o = (c & 3) << 3;
      gload_lds16(vp + (size_t)r * DIMK + k0 + o, &Bs[c * 8]);
    }
    __syncthreads();
    short8 af[4], bfv[8];
#pragma unroll
    for (int i = 0; i < 4; ++i)
      af[i] = *(const short8*)&As[(i * 16 + l16) * 32 + quad * 8];
#pragma unroll
    for (int j = 0; j < 8; ++j)
      bfv[j] = *(const short8*)&Bs[(wv * 128 + j * 16 + l16) * 32 + quad * 8];
#pragma unroll
    for (int i = 0; i < 4; ++i)
#pragma unroll
      for (int j = 0; j < 8; ++j)
        acc[i][j] = __builtin_amdgcn_mfma_f32_16x16x32_bf16(
            af[i], bfv[j], acc[i][j], 0, 0, 0);
    __syncthreads();
  }

  // ---- epilogue: + residual, LayerNorm over 512 dims ----
  float vsum[4][4], vsq[4][4];
#pragma unroll
  for (int i = 0; i < 4; ++i)
#pragma unroll
    for (int r = 0; r < 4; ++r) { vsum[i][r] = 0.f; vsq[i][r] = 0.f; }
#pragma unroll
  for (int i = 0; i < 4; ++i)
#pragma unroll
    for (int j = 0; j < 8; ++j)
#pragma unroll
      for (int r = 0; r < 4; ++r) {
        const size_t tok = q0 + i * 16 + quad * 4 + r;
        const int col = wv * 128 + j * 16 + l16;
        const float v = acc[i][j][r] + X[tok * (size_t)DIMK + col];
        acc[i][j][r] = v;
        vsum[i][r] += v;
        vsq[i][r] += v * v;
      }
#pragma unroll
  for (int i = 0; i < 4; ++i)
#pragma unroll
    for (int r = 0; r < 4; ++r)
      for (int d = 1; d < 16; d <<= 1) {
        vsum[i][r] += __shfl_xor(vsum[i][r], d, 64);
        vsq[i][r]  += __shfl_xor(vsq[i][r], d, 64);
      }
  if (l16 == 0)
#pragma unroll
    for (int i = 0; i < 4; ++i)
#pragma unroll
      for (int r = 0; r < 4; ++r) {
        float2 p; p.x = vsum[i][r]; p.y = vsq[i][r];
        red[wv][i * 16 + quad * 4 + r] = p;
      }
  __syncthreads();
#pragma unroll
  for (int i = 0; i < 4; ++i)
#pragma unroll
    for (int r = 0; r < 4; ++r) {
      const int row = i * 16 + quad * 4 + r;
      float s = 0.f, q = 0.f;
#pragma unroll
      for (int w = 0; w < 4; ++w) { s += red[w][row].x; q += red[w][row].y; }
      const float mean = s * (1.0f / 512.0f);
      const float var  = q * (1.0f / 512.0f) - mean * mean;
      vsum[i][r] = mean;
      vsq[i][r]  = rsqrtf(var + 1e-3f);
    }
#pragma unroll
  for (int i = 0; i < 4; ++i)
#pragma unroll
    for (int j = 0; j < 8; ++j)
#pragma unroll
      for (int r = 0; r < 4; ++r) {
        const size_t tok = q0 + i * 16 + quad * 4 + r;
        const int col = wv * 128 + j * 16 + l16;
        Out[tok * (size_t)DIMK + col] =
            (acc[i][j][r] - vsum[i][r]) * vsq[i][r];
      }
}

// ---------------------------------------------------------------------------
extern "C" void kernel_launch(void* const* d_in, const int* in_sizes, int n_in,
                              void* d_out, int out_size, void* d_ws, size_t ws_size,
                              hipStream_t stream)
{
  const float* X    = (const float*)d_in[0];
  const float* mask = (const float*)d_in[1];
  const float* dw1  = (const float*)d_in[2];
  const float* dw2  = (const float*)d_in[3];
  const float* dw3  = (const float*)d_in[4];
  const float* db1  = (const float*)d_in[5];
  const float* db2  = (const float*)d_in[6];
  const float* db3  = (const float*)d_in[7];
  float* Out = (float*)d_out;

  char* ws = (char*)d_ws;
  const size_t MB = 1ull << 20;
  const bool big = ws_size >= 132 * MB;   // room for 2 MB bitmask?

  // layout: Wt [0,2), (bits [2,4) if big), then Qb/Kb/Vt/Pb 32 MB each
  unsigned short* Wt = (unsigned short*)(ws);
  unsigned char*  bits = (unsigned char*)(ws + 2 * MB);
  const size_t base = big ? 4 * MB : 2 * MB;
  unsigned short* Qb = (unsigned short*)(ws + base);
  unsigned short* Kb = (unsigned short*)(ws + base + 32 * MB);
  unsigned short* Vt = (unsigned short*)(ws + base + 64 * MB);
  unsigned short* Pb = (unsigned short*)(ws + base + 96 * MB);
  unsigned short* Xb = Pb;   // alias: dead once k_qkv completes

  k_wt_prep<<<3072, 256, 0, stream>>>(dw1, dw2, dw3, Wt);
  if (big)
    k_xconv<true><<<8192, 256, 0, stream>>>(X, mask, Xb, bits);
  else
    k_xconv<false><<<8192, 256, 0, stream>>>(X, mask, Xb, bits);
  k_qkv<<<3072, 256, 0, stream>>>(Xb, Wt, db1, db2, db3, Qb, Kb, Vt);
  if (big)
    k_attn_p<true><<<512, 256, 0, stream>>>(
        Qb, Kb, mask, (const unsigned long long*)bits, Pb);
  else
    k_attn_p<false><<<512, 256, 0, stream>>>(
        Qb, Kb, mask, (const unsigned long long*)bits, Pb);
  k_pv_ln<<<512, 256, 0, stream>>>(Pb, Vt, X, Out);
}

// Round 4
// 344.466 us; speedup vs baseline: 1.2549x; 1.0229x over previous
//
#include <hip/hip_runtime.h>

#define DIMK 512
#define NBLK 64
#define NTOK 32768

typedef short  short8 __attribute__((ext_vector_type(8)));
typedef float  f32x4  __attribute__((ext_vector_type(4)));
typedef unsigned short u16x8 __attribute__((ext_vector_type(8)));

__device__ __forceinline__ unsigned short f2bf(float f) {
  union { float f; unsigned u; } v; v.f = f;
  unsigned r = (v.u + 0x7FFFu + ((v.u >> 16) & 1u)) >> 16;   // RNE
  return (unsigned short)r;
}
__device__ __forceinline__ float bf2f(unsigned short h) {
  return __uint_as_float(((unsigned)h) << 16);
}

// async 16B global -> LDS (wave-uniform base + lane*16)
__device__ __forceinline__ void gload_lds16(const unsigned short* g,
                                            unsigned short* l) {
  __builtin_amdgcn_global_load_lds(
      (const __attribute__((address_space(1))) unsigned int*)(g),
      (__attribute__((address_space(3))) unsigned int*)(l),
      16, 0, 0);
}

// ---------------------------------------------------------------------------
// K0a: Wt[w][n][k] = bf16(dw_w[k][n])
// ---------------------------------------------------------------------------
__global__ __launch_bounds__(256) void k_wt_prep(
    const float* __restrict__ dw1, const float* __restrict__ dw2,
    const float* __restrict__ dw3, unsigned short* __restrict__ Wt)
{
  const int idx = blockIdx.x * 256 + threadIdx.x;
  const int w = idx >> 18;
  const int r = idx & 262143;
  const int n = r >> 9, k = r & 511;
  const float* dw = (w == 0) ? dw1 : (w == 1) ? dw2 : dw3;
  Wt[(size_t)w * 262144 + (size_t)n * 512 + k] = f2bf(dw[(size_t)k * 512 + n]);
}

// ---------------------------------------------------------------------------
// K0b: X fp32 -> bf16 bits
// ---------------------------------------------------------------------------
__global__ __launch_bounds__(256) void k_xconv(
    const float* __restrict__ X, unsigned short* __restrict__ Xb)
{
  const size_t i = ((size_t)blockIdx.x * 256 + threadIdx.x) * 8;
  const float4 a = *(const float4*)(X + i);
  const float4 b = *(const float4*)(X + i + 4);
  u16x8 o;
  o[0] = f2bf(a.x); o[1] = f2bf(a.y); o[2] = f2bf(a.z); o[3] = f2bf(a.w);
  o[4] = f2bf(b.x); o[5] = f2bf(b.y); o[6] = f2bf(b.z); o[7] = f2bf(b.w);
  *(u16x8*)(Xb + i) = o;
}

// ---------------------------------------------------------------------------
// K0c: pack mask {0,1} -> bitmask, 1 byte per thread (bits buffer = d_out head)
// ---------------------------------------------------------------------------
__global__ __launch_bounds__(256) void k_bitpack(
    const float* __restrict__ mask, unsigned char* __restrict__ bits)
{
  const size_t gid = (size_t)blockIdx.x * 256 + threadIdx.x;
  const size_t i = gid * 8;
  const float4 ma = *(const float4*)(mask + i);
  const float4 mb = *(const float4*)(mask + i + 4);
  unsigned v = 0;
  v |= (ma.x > 0.5f) << 0; v |= (ma.y > 0.5f) << 1;
  v |= (ma.z > 0.5f) << 2; v |= (ma.w > 0.5f) << 3;
  v |= (mb.x > 0.5f) << 4; v |= (mb.y > 0.5f) << 5;
  v |= (mb.z > 0.5f) << 6; v |= (mb.w > 0.5f) << 7;
  bits[gid] = (unsigned char)v;
}

// ---------------------------------------------------------------------------
// K1: merged QKV. Block (mtile, nt) computes Q,K,V 128x128 tiles sharing one
// A-staging. Decode: x = id&7 (XCD), j = id>>3; mtile = x*32 + (j>>2), nt=j&3.
// V written transposed per block via padded-LDS epilogue (coalesced stores).
// ---------------------------------------------------------------------------
__global__ __launch_bounds__(256, 2) void k_qkv(
    const unsigned short* __restrict__ Xb, const unsigned short* __restrict__ Wt,
    const float* __restrict__ db1, const float* __restrict__ db2,
    const float* __restrict__ db3,
    unsigned short* __restrict__ Qb, unsigned short* __restrict__ Kb,
    unsigned short* __restrict__ Vt)
{
  // smem: gemm uses [0,16384) elems (As 128x32 @0, Bs_w 128x32 @4096*(1+w));
  // V-transpose epilogue reuses [0, 128*136) elems (34 KB, stride 136:
  // 16B-aligned rows, 2-way bank alias = free).
  __shared__ __align__(16) unsigned short smem[128 * 136];
  unsigned short* As = smem;
  unsigned short* Bs = smem + 4096;

  const int id = blockIdx.x;
  const int x = id & 7, j = id >> 3;
  const int mtile = x * 32 + (j >> 2);
  const int nt = j & 3;
  const size_t m0 = (size_t)mtile * 128;
  const int n0 = nt * 128;

  const int tid = threadIdx.x, lane = tid & 63, wv = tid >> 6;
  const int quad = lane >> 4, l16 = lane & 15;
  const int rb = (wv >> 1) * 64, cb = (wv & 1) * 64;

  f32x4 acc[3][4][4];
#pragma unroll
  for (int w = 0; w < 3; ++w)
#pragma unroll
    for (int i = 0; i < 4; ++i)
#pragma unroll
      for (int jj = 0; jj < 4; ++jj) {
        f32x4 z = {0.f, 0.f, 0.f, 0.f}; acc[w][i][jj] = z;
      }

  // A-chunk addresses (2 per thread), B-chunks (6 per thread over 3 weights)
  const int ra0 = tid >> 2,          oa0 = (tid & 3) << 3;
  const int ra1 = (tid + 256) >> 2,  oa1 = ((tid + 256) & 3) << 3;
  const unsigned short* a0 = &Xb[(m0 + ra0) * (size_t)DIMK + oa0];
  const unsigned short* a1 = &Xb[(m0 + ra1) * (size_t)DIMK + oa1];

  for (int it = 0; it < 16; ++it) {
    const int k0 = it * 32;
    gload_lds16(a0 + k0, &As[tid * 8]);
    gload_lds16(a1 + k0, &As[(tid + 256) * 8]);
#pragma unroll
    for (int h = 0; h < 6; ++h) {
      const int c = tid + h * 256;          // 0..1535
      const int w = c >> 9, cc = c & 511;
      const int r = cc >> 2, o = (cc & 3) << 3;
      gload_lds16(&Wt[(size_t)w * 262144 + (size_t)(n0 + r) * 512 + k0 + o],
                  &Bs[w * 4096 + cc * 8]);
    }
    __syncthreads();
    short8 af[4];
#pragma unroll
    for (int i = 0; i < 4; ++i)
      af[i] = *(const short8*)&As[(rb + i * 16 + l16) * 32 + quad * 8];
#pragma unroll
    for (int jj = 0; jj < 4; ++jj)
#pragma unroll
      for (int w = 0; w < 3; ++w) {
        const short8 bf =
            *(const short8*)&Bs[w * 4096 + (cb + jj * 16 + l16) * 32 + quad * 8];
#pragma unroll
        for (int i = 0; i < 4; ++i)
          acc[w][i][jj] = __builtin_amdgcn_mfma_f32_16x16x32_bf16(
              af[i], bf, acc[w][i][jj], 0, 0, 0);
      }
    __syncthreads();
  }

  // ---- epilogue: Q, K direct stores ----
#pragma unroll
  for (int w = 0; w < 2; ++w) {
    const float* db = (w == 0) ? db1 : db2;
    unsigned short* Ob = (w == 0) ? Qb : Kb;
#pragma unroll
    for (int i = 0; i < 4; ++i)
#pragma unroll
      for (int jj = 0; jj < 4; ++jj)
#pragma unroll
        for (int r = 0; r < 4; ++r) {
          const size_t row = m0 + rb + i * 16 + quad * 4 + r;
          const int col = n0 + cb + jj * 16 + l16;
          Ob[row * (size_t)DIMK + col] = f2bf(acc[w][i][jj][r] + db[col]);
        }
  }
  // ---- V: LDS transpose (L[col][tok], stride 136) then coalesced stores ----
#pragma unroll
  for (int i = 0; i < 4; ++i)
#pragma unroll
    for (int jj = 0; jj < 4; ++jj) {
      const int cl = cb + jj * 16 + l16;          // local col 0..127
      const int t0 = rb + i * 16 + quad * 4;      // local tok 0..127 (x4)
      const float bv = db3[n0 + cl];
      ushort4 pk;
      pk.x = f2bf(acc[2][i][jj][0] + bv);
      pk.y = f2bf(acc[2][i][jj][1] + bv);
      pk.z = f2bf(acc[2][i][jj][2] + bv);
      pk.w = f2bf(acc[2][i][jj][3] + bv);
      *(ushort4*)&smem[cl * 136 + t0] = pk;
    }
  __syncthreads();
  const int blk = mtile >> 2;
  const int tokbase = (mtile & 3) * 128;
  unsigned short* Vblk = Vt + (size_t)blk * 262144;
#pragma unroll
  for (int h = 0; h < 8; ++h) {
    const int c = tid + h * 256;                  // 2048 16B chunks
    const int cl = c >> 4, toff = (c & 15) * 8;
    *(u16x8*)&Vblk[(size_t)(n0 + cl) * 512 + tokbase + toff] =
        *(const u16x8*)&smem[cl * 136 + toff];
  }
}

// ---------------------------------------------------------------------------
// K2: fused scores + mask(bits) + softmax -> P (bf16), P overwrites Q.
// Flat grid 512: blk = id & 63 (XCD-coherent), mt = id >> 6.
// ---------------------------------------------------------------------------
__global__ __launch_bounds__(256, 2) void k_attn_p(
    const unsigned short* __restrict__ Qb, const unsigned short* __restrict__ Kb,
    const unsigned long long* __restrict__ bits, unsigned short* __restrict__ Pb)
{
  __shared__ __align__(16) unsigned short As[64 * 32];
  __shared__ __align__(16) unsigned short Bs[512 * 32];
  __shared__ float red[4][64];
  const int tid = threadIdx.x, lane = tid & 63, wv = tid >> 6;
  const int quad = lane >> 4, l16 = lane & 15;
  const int blk = blockIdx.x & 63, mt = blockIdx.x >> 6;
  const size_t tb = (size_t)blk * 512;
  const size_t q0 = tb + (size_t)mt * 64;

  f32x4 acc[4][8];
#pragma unroll
  for (int i = 0; i < 4; ++i)
#pragma unroll
    for (int j = 0; j < 8; ++j) { f32x4 z = {0.f, 0.f, 0.f, 0.f}; acc[i][j] = z; }

  const int ra = tid >> 2, oa = (tid & 3) << 3;
  const unsigned short* ap = &Qb[(q0 + ra) * (size_t)DIMK + oa];
  const unsigned short* kp = &Kb[tb * (size_t)DIMK];

  for (int it = 0; it < 16; ++it) {
    const int k0 = it * 32;
    gload_lds16(ap + k0, &As[tid * 8]);
#pragma unroll
    for (int h = 0; h < 8; ++h) {
      const int c = tid + h * 256;
      const int r = c >> 2, o = (c & 3) << 3;
      gload_lds16(kp + (size_t)r * DIMK + k0 + o, &Bs[c * 8]);
    }
    __syncthreads();
    short8 af[4], bfv[8];
#pragma unroll
    for (int i = 0; i < 4; ++i)
      af[i] = *(const short8*)&As[(i * 16 + l16) * 32 + quad * 8];
#pragma unroll
    for (int j = 0; j < 8; ++j)
      bfv[j] = *(const short8*)&Bs[(wv * 128 + j * 16 + l16) * 32 + quad * 8];
#pragma unroll
    for (int i = 0; i < 4; ++i)
#pragma unroll
      for (int j = 0; j < 8; ++j)
        acc[i][j] = __builtin_amdgcn_mfma_f32_16x16x32_bf16(
            af[i], bfv[j], acc[i][j], 0, 0, 0);
    __syncthreads();
  }

  const float scale = 0.04419417382415922f;   // 1/sqrt(512)
  float rmax[4][4];
#pragma unroll
  for (int i = 0; i < 4; ++i)
#pragma unroll
    for (int r = 0; r < 4; ++r) rmax[i][r] = -3.0e38f;
#pragma unroll
  for (int i = 0; i < 4; ++i)
#pragma unroll
    for (int r = 0; r < 4; ++r) {
      const size_t tok = q0 + i * 16 + quad * 4 + r;
      const unsigned long long w0 = bits[tok * 8 + wv * 2];
      const unsigned long long w1 = bits[tok * 8 + wv * 2 + 1];
#pragma unroll
      for (int j = 0; j < 8; ++j) {
        const unsigned long long sel = (j < 4) ? w0 : w1;
        const float bias = ((sel >> (l16 + 16 * (j & 3))) & 1ull) ? 0.0f : -1e10f;
        const float v = acc[i][j][r] * scale + bias;
        acc[i][j][r] = v;
        rmax[i][r] = fmaxf(rmax[i][r], v);
      }
    }
#pragma unroll
  for (int i = 0; i < 4; ++i)
#pragma unroll
    for (int r = 0; r < 4; ++r)
      for (int d = 1; d < 16; d <<= 1)
        rmax[i][r] = fmaxf(rmax[i][r], __shfl_xor(rmax[i][r], d, 64));
  if (l16 == 0)
#pragma unroll
    for (int i = 0; i < 4; ++i)
#pragma unroll
      for (int r = 0; r < 4; ++r) red[wv][i * 16 + quad * 4 + r] = rmax[i][r];
  __syncthreads();
#pragma unroll
  for (int i = 0; i < 4; ++i)
#pragma unroll
    for (int r = 0; r < 4; ++r) {
      const int row = i * 16 + quad * 4 + r;
      rmax[i][r] = fmaxf(fmaxf(red[0][row], red[1][row]),
                         fmaxf(red[2][row], red[3][row]));
    }
  __syncthreads();
  float rsum[4][4];
#pragma unroll
  for (int i = 0; i < 4; ++i)
#pragma unroll
    for (int r = 0; r < 4; ++r) rsum[i][r] = 0.f;
#pragma unroll
  for (int i = 0; i < 4; ++i)
#pragma unroll
    for (int j = 0; j < 8; ++j)
#pragma unroll
      for (int r = 0; r < 4; ++r) {
        const float e = __expf(acc[i][j][r] - rmax[i][r]);
        acc[i][j][r] = e;
        rsum[i][r] += e;
      }
#pragma unroll
  for (int i = 0; i < 4; ++i)
#pragma unroll
    for (int r = 0; r < 4; ++r)
      for (int d = 1; d < 16; d <<= 1)
        rsum[i][r] += __shfl_xor(rsum[i][r], d, 64);
  if (l16 == 0)
#pragma unroll
    for (int i = 0; i < 4; ++i)
#pragma unroll
      for (int r = 0; r < 4; ++r) red[wv][i * 16 + quad * 4 + r] = rsum[i][r];
  __syncthreads();
#pragma unroll
  for (int i = 0; i < 4; ++i)
#pragma unroll
    for (int r = 0; r < 4; ++r) {
      const int row = i * 16 + quad * 4 + r;
      rsum[i][r] = 1.0f / (red[0][row] + red[1][row] + red[2][row] + red[3][row]);
    }
#pragma unroll
  for (int i = 0; i < 4; ++i)
#pragma unroll
    for (int j = 0; j < 8; ++j)
#pragma unroll
      for (int r = 0; r < 4; ++r) {
        const size_t tok = q0 + i * 16 + quad * 4 + r;
        const int col = wv * 128 + j * 16 + l16;
        Pb[tok * (size_t)DIMK + col] = f2bf(acc[i][j][r] * rsum[i][r]);
      }
}

// ---------------------------------------------------------------------------
// K3: fused PV + residual(bf16 Xb) + LayerNorm -> Out (fp32).
// Flat grid 512: blk = id & 63, mt = id >> 6.
// ---------------------------------------------------------------------------
__global__ __launch_bounds__(256, 2) void k_pv_ln(
    const unsigned short* __restrict__ Pb, const unsigned short* __restrict__ Vt,
    const unsigned short* __restrict__ Xb, float* __restrict__ Out)
{
  __shared__ __align__(16) unsigned short As[64 * 32];
  __shared__ __align__(16) unsigned short Bs[512 * 32];
  __shared__ float2 red[4][64];
  const int tid = threadIdx.x, lane = tid & 63, wv = tid >> 6;
  const int quad = lane >> 4, l16 = lane & 15;
  const int blk = blockIdx.x & 63, mt = blockIdx.x >> 6;
  const size_t tb = (size_t)blk * 512;
  const size_t q0 = tb + (size_t)mt * 64;

  f32x4 acc[4][8];
#pragma unroll
  for (int i = 0; i < 4; ++i)
#pragma unroll
    for (int j = 0; j < 8; ++j) { f32x4 z = {0.f, 0.f, 0.f, 0.f}; acc[i][j] = z; }

  const int ra = tid >> 2, oa = (tid & 3) << 3;
  const unsigned short* ap = &Pb[(q0 + ra) * (size_t)DIMK + oa];
  const unsigned short* vp = Vt + (size_t)blk * 262144;   // [d][tok]

  for (int it = 0; it < 16; ++it) {
    const int k0 = it * 32;
    gload_lds16(ap + k0, &As[tid * 8]);
#pragma unroll
    for (int h = 0; h < 8; ++h) {
      const int c = tid + h * 256;
      const int r = c >> 2, o = (c & 3) << 3;
      gload_lds16(vp + (size_t)r * DIMK + k0 + o, &Bs[c * 8]);
    }
    __syncthreads();
    short8 af[4], bfv[8];
#pragma unroll
    for (int i = 0; i < 4; ++i)
      af[i] = *(const short8*)&As[(i * 16 + l16) * 32 + quad * 8];
#pragma unroll
    for (int j = 0; j < 8; ++j)
      bfv[j] = *(const short8*)&Bs[(wv * 128 + j * 16 + l16) * 32 + quad * 8];
#pragma unroll
    for (int i = 0; i < 4; ++i)
#pragma unroll
      for (int j = 0; j < 8; ++j)
        acc[i][j] = __builtin_amdgcn_mfma_f32_16x16x32_bf16(
            af[i], bfv[j], acc[i][j], 0, 0, 0);
    __syncthreads();
  }

  float vsum[4][4], vsq[4][4];
#pragma unroll
  for (int i = 0; i < 4; ++i)
#pragma unroll
    for (int r = 0; r < 4; ++r) { vsum[i][r] = 0.f; vsq[i][r] = 0.f; }
#pragma unroll
  for (int i = 0; i < 4; ++i)
#pragma unroll
    for (int j = 0; j < 8; ++j)
#pragma unroll
      for (int r = 0; r < 4; ++r) {
        const size_t tok = q0 + i * 16 + quad * 4 + r;
        const int col = wv * 128 + j * 16 + l16;
        const float v = acc[i][j][r] + bf2f(Xb[tok * (size_t)DIMK + col]);
        acc[i][j][r] = v;
        vsum[i][r] += v;
        vsq[i][r] += v * v;
      }
#pragma unroll
  for (int i = 0; i < 4; ++i)
#pragma unroll
    for (int r = 0; r < 4; ++r)
      for (int d = 1; d < 16; d <<= 1) {
        vsum[i][r] += __shfl_xor(vsum[i][r], d, 64);
        vsq[i][r]  += __shfl_xor(vsq[i][r], d, 64);
      }
  if (l16 == 0)
#pragma unroll
    for (int i = 0; i < 4; ++i)
#pragma unroll
      for (int r = 0; r < 4; ++r) {
        float2 p; p.x = vsum[i][r]; p.y = vsq[i][r];
        red[wv][i * 16 + quad * 4 + r] = p;
      }
  __syncthreads();
#pragma unroll
  for (int i = 0; i < 4; ++i)
#pragma unroll
    for (int r = 0; r < 4; ++r) {
      const int row = i * 16 + quad * 4 + r;
      float s = 0.f, q = 0.f;
#pragma unroll
      for (int w = 0; w < 4; ++w) { s += red[w][row].x; q += red[w][row].y; }
      const float mean = s * (1.0f / 512.0f);
      const float var  = q * (1.0f / 512.0f) - mean * mean;
      vsum[i][r] = mean;
      vsq[i][r]  = rsqrtf(var + 1e-3f);
    }
#pragma unroll
  for (int i = 0; i < 4; ++i)
#pragma unroll
    for (int j = 0; j < 8; ++j)
#pragma unroll
      for (int r = 0; r < 4; ++r) {
        const size_t tok = q0 + i * 16 + quad * 4 + r;
        const int col = wv * 128 + j * 16 + l16;
        Out[tok * (size_t)DIMK + col] =
            (acc[i][j][r] - vsum[i][r]) * vsq[i][r];
      }
}

// ---------------------------------------------------------------------------
extern "C" void kernel_launch(void* const* d_in, const int* in_sizes, int n_in,
                              void* d_out, int out_size, void* d_ws, size_t ws_size,
                              hipStream_t stream)
{
  const float* X    = (const float*)d_in[0];
  const float* mask = (const float*)d_in[1];
  const float* dw1  = (const float*)d_in[2];
  const float* dw2  = (const float*)d_in[3];
  const float* dw3  = (const float*)d_in[4];
  const float* db1  = (const float*)d_in[5];
  const float* db2  = (const float*)d_in[6];
  const float* db3  = (const float*)d_in[7];
  float* Out = (float*)d_out;

  char* ws = (char*)d_ws;
  const size_t MB = 1ull << 20;
  // ws (130 MB): [Wt 2 | Qb/Pb 32 | Kb 32 | Vt 32 | Xb 32]
  // bits (2.1 MB) live in d_out's head: written post-xconv, consumed by
  // k_attn_p, then d_out fully overwritten by k_pv_ln (stream-ordered).
  unsigned short* Wt = (unsigned short*)(ws);
  unsigned short* Qb = (unsigned short*)(ws + 2 * MB);
  unsigned short* Kb = (unsigned short*)(ws + 34 * MB);
  unsigned short* Vt = (unsigned short*)(ws + 66 * MB);
  unsigned short* Xb = (unsigned short*)(ws + 98 * MB);
  unsigned short* Pb = Qb;                      // alias: safe (own-rows only)
  unsigned char*  bits = (unsigned char*)d_out;

  k_wt_prep<<<3072, 256, 0, stream>>>(dw1, dw2, dw3, Wt);
  k_xconv  <<<8192, 256, 0, stream>>>(X, Xb);
  k_bitpack<<<8192, 256, 0, stream>>>(mask, bits);
  k_qkv    <<<1024, 256, 0, stream>>>(Xb, Wt, db1, db2, db3, Qb, Kb, Vt);
  k_attn_p <<<512, 256, 0, stream>>>(Qb, Kb, (const unsigned long long*)bits, Pb);
  k_pv_ln  <<<512, 256, 0, stream>>>(Pb, Vt, Xb, Out);
}